// Round 3
// baseline (304.325 us; speedup 1.0000x reference)
//
#include <hip/hip_runtime.h>
#include <cstdint>
#include <cstddef>

#define NSLOPE 0.2f

typedef __attribute__((ext_vector_type(8))) short bf16x8;
typedef __attribute__((ext_vector_type(4))) float f32x4;
typedef __attribute__((ext_vector_type(2))) float f32x2;
typedef unsigned short ushort_t;

// ---------------------------------------------------------------- utilities
__device__ inline ushort_t f2bf(float f) {
    union { float f; unsigned u; } v; v.f = f;
    unsigned u = v.u;
    unsigned r = (u + 0x7fffu + ((u >> 16) & 1u)) >> 16;   // RNE
    return (ushort_t)r;
}
// optimal 2-op unpack: lo = u<<16, hi = u & 0xffff0000
__device__ inline f32x2 unpack2(unsigned u) {
    union { unsigned u; float f; } lo, hi;
    lo.u = u << 16;
    hi.u = u & 0xffff0000u;
    f32x2 r; r.x = lo.f; r.y = hi.f;
    return r;
}
__device__ inline float leaky(float v) { return (v > 0.f) ? v : NSLOPE * v; }
__device__ inline float sel4(float4 q, bool b1, bool b2) {
    return b2 ? (b1 ? q.w : q.z) : (b1 ? q.y : q.x);
}

// ---------------------------------------------------------------- fused prep
// x->bf16 cast REMOVED (GEMM1 now reads fp32 x directly and converts during
// staging). sections: [0,384) transpose W1 | [..+64) transpose W2 | [..+16)
// svec partials | [..+nbZero) zero indeg
__global__ __launch_bounds__(256) void prep_kernel(
    const float* __restrict__ W1, ushort_t* __restrict__ W1T,
    const float* __restrict__ W2, ushort_t* __restrict__ W2T,
    const float* __restrict__ sent, float* __restrict__ svec_part,
    int* __restrict__ indeg, int N, int nbZero)
{
    __shared__ float tile[32][33];
    int bid = blockIdx.x;
    int tid = threadIdx.x;
    if (bid < 384) {   // W1[768][512] -> W1T[512][768]
        int k0 = (bid % 24) * 32, n0 = (bid / 24) * 32;
        int tx = tid & 31, ty = tid >> 5;
#pragma unroll
        for (int i = 0; i < 4; ++i)
            tile[ty + i * 8][tx] = W1[(size_t)(k0 + ty + i * 8) * 512 + n0 + tx];
        __syncthreads();
#pragma unroll
        for (int i = 0; i < 4; ++i)
            W1T[(size_t)(n0 + ty + i * 8) * 768 + k0 + tx] = f2bf(tile[tx][ty + i * 8]);
        return;
    }
    bid -= 384;
    if (bid < 64) {    // W2[512][128] -> W2T[128][512]
        int k0 = (bid % 16) * 32, n0 = (bid / 16) * 32;
        int tx = tid & 31, ty = tid >> 5;
#pragma unroll
        for (int i = 0; i < 4; ++i)
            tile[ty + i * 8][tx] = W2[(size_t)(k0 + ty + i * 8) * 128 + n0 + tx];
        __syncthreads();
#pragma unroll
        for (int i = 0; i < 4; ++i)
            W2T[(size_t)(n0 + ty + i * 8) * 512 + k0 + tx] = f2bf(tile[tx][ty + i * 8]);
        return;
    }
    bid -= 64;
    if (bid < 16) {    // svec partials
        int cb = bid & 1, kb = bid >> 1;
        int c = cb * 256 + tid;
        int k0 = kb * 96;
        float acc = 0.f;
#pragma unroll 8
        for (int k = k0; k < k0 + 96; ++k)
            acc += sent[k] * W1[(size_t)(768 + k) * 512 + c];
        svec_part[kb * 512 + c] = acc;
        return;
    }
    bid -= 16;
    {                  // zero indeg
        int i = bid * 256 + tid;
        if (i < N) indeg[i] = 0;
    }
}

// ---------------------------------------------------------------- MFMA GEMM
// AFP32=true: A is fp32; A-staging is reg-staged (T14 split: dwordx4 loads for
// tile t+2 issued early, f2bf convert + ds_write_b128 for tile t+1 done late
// behind vmcnt(8)) — this fuses the x->bf16 cast into GEMM1 and deletes the
// 92MB cast pre-pass. B stays on the linear global_load_lds path (3-deep,
// counted vmcnt). AFP32=false: original all-global_load_lds path (GEMM2).
// XCD-aware bijective swizzle (gridDim.y % 8 == 0) groups the gridDim.x
// col-blocks of each A row-panel on one XCD (FETCH 61.6->20.0 MB measured).
// Fused attention-coefficient epilogue writes e_src/e_dst[row*eStride + bx].
__device__ inline void async_copy16(const void* g, void* l) {
    __builtin_amdgcn_global_load_lds(
        (const __attribute__((address_space(1))) unsigned int*)g,
        (__attribute__((address_space(3))) unsigned int*)l, 16, 0, 0);
}

template <bool AFP32>
__global__ __launch_bounds__(256) void mfma_gemm_kernel(
    const void* __restrict__ Ain,     // [M][K] bf16 (AFP32=0) or fp32 (AFP32=1)
    const ushort_t* __restrict__ BT,  // [Nc][K] bf16
    const float* __restrict__ bias,   // [Nc] or null
    ushort_t* __restrict__ Cb,        // [M][Nc] bf16
    const float* __restrict__ asrc,   // [Nc] flat attention vec (src)
    const float* __restrict__ adst,   // [Nc] flat attention vec (dst)
    float* __restrict__ e_src,        // [M*eStride]
    float* __restrict__ e_dst,
    int eStride,
    int M, int K, int Nc)
{
    __shared__ __align__(16) ushort_t lA[3][128 * 32];
    __shared__ __align__(16) ushort_t lB[3][128 * 32];
    __shared__ float e_lds[128][2][2];   // [row_local][col_half][src/dst]
    const int tid = threadIdx.x;
    const int wave = tid >> 6;
    const int lane = tid & 63;

    // bijective XCD swizzle (m204 form). Requires (gridDim.x*gridDim.y)%8==0.
    const int hh = blockIdx.y * gridDim.x + blockIdx.x;
    const int xcd = hh & 7;
    const int slot = hh >> 3;
    const int by = xcd + 8 * (slot / gridDim.x);
    const int bx = slot % gridDim.x;

    const int col0 = bx * 128;
    const int row0 = by * 128;
    const int wm = (wave & 1) * 64;
    const int wn = (wave >> 1) * 64;
    const int q = lane >> 4;
    const int ml = lane & 15;

    const float* A32 = (const float*)Ain;
    const ushort_t* A16 = (const ushort_t*)Ain;

    f32x4 acc[4][4] = {};

    int rowS[2], gS[2];
#pragma unroll
    for (int i = 0; i < 2; ++i) {
        int p = wave * 128 + i * 64 + lane;
        int r = p >> 2, s = p & 3;
        rowS[i] = r;
        gS[i] = s ^ ((r >> 1) & 3);
    }

    const int nt = K >> 5;           // 24 (GEMM1) / 16 (GEMM2)

    if constexpr (!AFP32) {
        // -------- original path: A and B both via global_load_lds ----------
        auto stage = [&](int k0, int buf) {
#pragma unroll
            for (int i = 0; i < 2; ++i) {
                int pbs = wave * 128 + i * 64;
                int r = rowS[i];
                int ga = min(row0 + r, M - 1);
                async_copy16(A16 + (size_t)ga * K + k0 + gS[i] * 8, &lA[buf][(size_t)pbs * 8]);
                async_copy16(BT + (size_t)(col0 + r) * K + k0 + gS[i] * 8, &lB[buf][(size_t)pbs * 8]);
            }
        };
        stage(0, 0);
        if (nt > 1) {
            stage(32, 1);
            asm volatile("s_waitcnt vmcnt(4)\n\ts_barrier" ::: "memory");
        } else {
            asm volatile("s_waitcnt vmcnt(0)\n\ts_barrier" ::: "memory");
        }
        for (int t = 0; t < nt; ++t) {
            const int pb = t % 3;
            if (t + 2 < nt) stage((t + 2) << 5, (t + 2) % 3);
            bf16x8 af[4], bfr[4];
#pragma unroll
            for (int tt = 0; tt < 4; ++tt) {
                int m = wm + tt * 16 + ml;
                af[tt] = *(const bf16x8*)&lA[pb][(size_t)(m * 4 + (q ^ ((m >> 1) & 3))) * 8];
                int n = wn + tt * 16 + ml;
                bfr[tt] = *(const bf16x8*)&lB[pb][(size_t)(n * 4 + (q ^ ((n >> 1) & 3))) * 8];
            }
#pragma unroll
            for (int tm = 0; tm < 4; ++tm)
#pragma unroll
                for (int tn = 0; tn < 4; ++tn)
                    acc[tm][tn] = __builtin_amdgcn_mfma_f32_16x16x32_bf16(
                        af[tm], bfr[tn], acc[tm][tn], 0, 0, 0);
            if (t + 2 < nt)
                asm volatile("s_waitcnt vmcnt(4) lgkmcnt(0)\n\ts_barrier" ::: "memory");
            else if (t + 1 < nt)
                asm volatile("s_waitcnt vmcnt(0) lgkmcnt(0)\n\ts_barrier" ::: "memory");
        }
    } else {
        // -------- fused-cast path: A reg-staged fp32->bf16, B via lds ------
        auto loadA = [&](int k0, float4 (&dst)[4]) {
#pragma unroll
            for (int i = 0; i < 2; ++i) {
                int ga = min(row0 + rowS[i], M - 1);
                const float* src = A32 + (size_t)ga * K + k0 + gS[i] * 8;
                dst[2 * i]     = *(const float4*)src;
                dst[2 * i + 1] = *(const float4*)(src + 4);
            }
        };
        auto stageB = [&](int k0, int buf) {
#pragma unroll
            for (int i = 0; i < 2; ++i) {
                int pbs = wave * 128 + i * 64;
                async_copy16(BT + (size_t)(col0 + rowS[i]) * K + k0 + gS[i] * 8,
                             &lB[buf][(size_t)pbs * 8]);
            }
        };
        auto cvtWrite = [&](int buf, float4 (&cur)[4]) {
#pragma unroll
            for (int i = 0; i < 2; ++i) {
                float4 lo = cur[2 * i], hi = cur[2 * i + 1];
                ushort_t tmp[8] = { f2bf(lo.x), f2bf(lo.y), f2bf(lo.z), f2bf(lo.w),
                                    f2bf(hi.x), f2bf(hi.y), f2bf(hi.z), f2bf(hi.w) };
                *(uint4*)&lA[buf][(size_t)(wave * 128 + i * 64 + lane) * 8] = *(uint4*)tmp;
            }
        };

        float4 rEven[4], rOdd[4];
        // prologue: issue A(0)->rOdd, B(0), A(1)->rEven, B(1); publish tile 0.
        loadA(0, rOdd);
        stageB(0, 0);
        if (nt > 1) {
            loadA(32, rEven);
            stageB(32, 1);
            asm volatile("s_waitcnt vmcnt(8)" ::: "memory");   // A(0) done
            cvtWrite(0, rOdd);
            asm volatile("s_waitcnt vmcnt(6) lgkmcnt(0)\n\ts_barrier" ::: "memory");
        } else {
            asm volatile("s_waitcnt vmcnt(2)" ::: "memory");
            cvtWrite(0, rOdd);
            asm volatile("s_waitcnt vmcnt(0) lgkmcnt(0)\n\ts_barrier" ::: "memory");
        }

        auto body = [&](int t, float4 (&cur)[4], float4 (&nxt)[4]) {
            const int pb = t % 3;
            const bool has2 = (t + 2 < nt);
            if (has2) {
                int k0n = (t + 2) << 5;
                loadA(k0n, nxt);                 // A(t+2)x4 (regs)
                stageB(k0n, (t + 2) % 3);        // B(t+2)x2 (lds)
            }
            bf16x8 af[4], bfr[4];
#pragma unroll
            for (int tt = 0; tt < 4; ++tt) {
                int m = wm + tt * 16 + ml;
                af[tt] = *(const bf16x8*)&lA[pb][(size_t)(m * 4 + (q ^ ((m >> 1) & 3))) * 8];
                int n = wn + tt * 16 + ml;
                bfr[tt] = *(const bf16x8*)&lB[pb][(size_t)(n * 4 + (q ^ ((n >> 1) & 3))) * 8];
            }
#pragma unroll
            for (int tm = 0; tm < 4; ++tm)
#pragma unroll
                for (int tn = 0; tn < 4; ++tn)
                    acc[tm][tn] = __builtin_amdgcn_mfma_f32_16x16x32_bf16(
                        af[tm], bfr[tn], acc[tm][tn], 0, 0, 0);
            if (t + 1 < nt) {
                // publish tile t+1: A via cvt+ds_write (regs loaded last iter),
                // B via counted vmcnt. t+2's 6 VMEM ops stay IN FLIGHT.
                if (has2) asm volatile("s_waitcnt vmcnt(8)" ::: "memory");
                else      asm volatile("s_waitcnt vmcnt(2)" ::: "memory");
                cvtWrite((t + 1) % 3, cur);
                if (has2) asm volatile("s_waitcnt vmcnt(6) lgkmcnt(0)\n\ts_barrier" ::: "memory");
                else      asm volatile("s_waitcnt vmcnt(0) lgkmcnt(0)\n\ts_barrier" ::: "memory");
            }
        };

        for (int t = 0; t + 1 < nt; t += 2) {
            body(t, rEven, rOdd);
            body(t + 1, rOdd, rEven);
        }
        if (nt & 1) body(nt - 1, rEven, rOdd);
    }

    float es_acc[4][4] = {};   // [tm][r]
    float ed_acc[4][4] = {};
#pragma unroll
    for (int tm = 0; tm < 4; ++tm) {
        int rbase = row0 + wm + tm * 16 + q * 4;
#pragma unroll
        for (int tn = 0; tn < 4; ++tn) {
            int col = col0 + wn + tn * 16 + ml;
            float bb = bias ? bias[col] : 0.f;
            float av = asrc[col];
            float dv = adst[col];
#pragma unroll
            for (int r = 0; r < 4; ++r) {
                int row = rbase + r;
                float val = acc[tm][tn][r] + bb;
                if (row < M)
                    Cb[(size_t)row * Nc + col] = f2bf(val);
                es_acc[tm][r] += val * av;
                ed_acc[tm][r] += val * dv;
            }
        }
    }
    // reduce over the 16-lane col groups (xor 1,2,4,8 keeps q fixed)
    const int colhalf = wave >> 1;
#pragma unroll
    for (int tm = 0; tm < 4; ++tm) {
#pragma unroll
        for (int r = 0; r < 4; ++r) {
            float es = es_acc[tm][r], ed2 = ed_acc[tm][r];
#pragma unroll
            for (int st = 1; st < 16; st <<= 1) {
                es += __shfl_xor(es, st);
                ed2 += __shfl_xor(ed2, st);
            }
            if (ml == 0) {
                int rl = wm + tm * 16 + q * 4 + r;
                e_lds[rl][colhalf][0] = es;
                e_lds[rl][colhalf][1] = ed2;
            }
        }
    }
    __syncthreads();
    if (tid < 128) {
        int row = row0 + tid;
        if (row < M) {
            float es = e_lds[tid][0][0] + e_lds[tid][1][0];
            float ed2 = e_lds[tid][0][1] + e_lds[tid][1][1];
            e_src[(size_t)row * eStride + bx] = es;
            e_dst[(size_t)row * eStride + bx] = ed2;
        }
    }
}

// ---------------------------------------------------------------- CSR build
__global__ void count_kernel(const int* __restrict__ ei, int* __restrict__ indeg, int E) {
    int e = blockIdx.x * blockDim.x + threadIdx.x;
    if (e < E) atomicAdd(&indeg[ei[E + e]], 1);
}

__global__ __launch_bounds__(1024) void scan_kernel(const int* __restrict__ indeg,
                                                    int* __restrict__ offsets,
                                                    int* __restrict__ cursor,
                                                    const float* __restrict__ svec_part,
                                                    float* __restrict__ svec, int N) {
    __shared__ int partial[1024];
    int tid = threadIdx.x;
    if (tid < 512) {
        float s = 0.f;
#pragma unroll
        for (int kb = 0; kb < 8; ++kb) s += svec_part[kb * 512 + tid];
        svec[tid] = s;
    }
    int per = (N + 1023) / 1024;
    int start = tid * per;
    int end = min(start + per, N);
    int sum = 0;
    if (start + per <= N && (per & 3) == 0) {
        for (int i = 0; i < per; i += 4) {
            int4 v = *(const int4*)(indeg + start + i);
            sum += v.x + v.y + v.z + v.w;
        }
    } else {
        for (int i = start; i < end; ++i) sum += indeg[i];
    }
    partial[tid] = sum;
    __syncthreads();
    for (int st = 1; st < 1024; st <<= 1) {
        int v = (tid >= st) ? partial[tid - st] : 0;
        __syncthreads();
        partial[tid] += v;
        __syncthreads();
    }
    int run = (tid == 0) ? 0 : partial[tid - 1];
    if (start + per <= N && (per & 3) == 0) {
        for (int i = 0; i < per; i += 4) {
            int4 v = *(const int4*)(indeg + start + i);
            int4 o;
            o.x = run;
            o.y = o.x + v.x;
            o.z = o.y + v.y;
            o.w = o.z + v.z;
            run = o.w + v.w;
            *(int4*)(offsets + start + i) = o;
            *(int4*)(cursor + start + i) = o;
        }
    } else {
        for (int i = start; i < end; ++i) {
            offsets[i] = run; cursor[i] = run;
            run += indeg[i];
        }
    }
    if (tid == 1023) offsets[N] = run;
}

__global__ void scatter_kernel(const int* __restrict__ ei, int* __restrict__ cursor,
                               int* __restrict__ csr_src, int E) {
    int e = blockIdx.x * blockDim.x + threadIdx.x;
    if (e < E) {
        int d = ei[E + e];
        int p = atomicAdd(&cursor[d], 1);
        csr_src[p] = ei[e];
    }
}

// ---------------------------------------------------------------- gather+softmax
// layer 1: wave per node. Unnormalized softmax: degrees are small (Poisson(16))
// and e = leaky(e_src+e_dst) is bounded (max ~11 << 88 = fp32 exp overflow), so
// accumulate w = exp(e) and redundant per-lane s = sum(w); scale by 1/s at end.
__global__ __launch_bounds__(256) void gather1_kernel(
    const ushort_t* __restrict__ h1b, const float* __restrict__ e_src,
    const float* __restrict__ e_dst, const int* __restrict__ offsets,
    const int* __restrict__ csr_src, const float* __restrict__ bias,
    ushort_t* __restrict__ outb, int N)
{
    int node = __builtin_amdgcn_readfirstlane(blockIdx.x * 4 + (threadIdx.x >> 6));
    int lane = threadIdx.x & 63;
    if (node >= N) return;
    int beg = offsets[node], end = offsets[node + 1];
    float4 ed = *(const float4*)&e_dst[node * 4];

    // per-lane head constants
    const int h = lane >> 4;
    const bool b1 = (h & 1), b2 = (h & 2);
    float edh = sel4(ed, b1, b2);

    const ushort_t* hp = h1b + lane * 8;
    f32x2 acc[4] = {};
    float s = 0.f;                       // same value in every lane of a head
    int j = beg;
#pragma unroll 2
    for (; j + 4 <= end; j += 4) {
        int s0 = csr_src[j], s1 = csr_src[j + 1];          // scalar
        int s2 = csr_src[j + 2], s3 = csr_src[j + 3];
        float4 q0 = *(const float4*)&e_src[s0 * 4];        // scalar 16B
        float4 q1 = *(const float4*)&e_src[s1 * 4];
        float4 q2 = *(const float4*)&e_src[s2 * 4];
        float4 q3 = *(const float4*)&e_src[s3 * 4];
        float w0 = __expf(leaky(sel4(q0, b1, b2) + edh));
        float w1 = __expf(leaky(sel4(q1, b1, b2) + edh));
        float w2 = __expf(leaky(sel4(q2, b1, b2) + edh));
        float w3 = __expf(leaky(sel4(q3, b1, b2) + edh));
        s += (w0 + w1) + (w2 + w3);
        uint4 u0 = *(const uint4*)&hp[(size_t)s0 * 512];
        uint4 u1 = *(const uint4*)&hp[(size_t)s1 * 512];
        uint4 u2 = *(const uint4*)&hp[(size_t)s2 * 512];
        uint4 u3 = *(const uint4*)&hp[(size_t)s3 * 512];
        f32x2 wv;
        wv.x = w0; wv.y = w0;
        acc[0] += unpack2(u0.x) * wv; acc[1] += unpack2(u0.y) * wv;
        acc[2] += unpack2(u0.z) * wv; acc[3] += unpack2(u0.w) * wv;
        wv.x = w1; wv.y = w1;
        acc[0] += unpack2(u1.x) * wv; acc[1] += unpack2(u1.y) * wv;
        acc[2] += unpack2(u1.z) * wv; acc[3] += unpack2(u1.w) * wv;
        wv.x = w2; wv.y = w2;
        acc[0] += unpack2(u2.x) * wv; acc[1] += unpack2(u2.y) * wv;
        acc[2] += unpack2(u2.z) * wv; acc[3] += unpack2(u2.w) * wv;
        wv.x = w3; wv.y = w3;
        acc[0] += unpack2(u3.x) * wv; acc[1] += unpack2(u3.y) * wv;
        acc[2] += unpack2(u3.z) * wv; acc[3] += unpack2(u3.w) * wv;
    }
    for (; j < end; ++j) {
        int s0 = csr_src[j];
        float4 q0 = *(const float4*)&e_src[s0 * 4];
        float w0 = __expf(leaky(sel4(q0, b1, b2) + edh));
        s += w0;
        uint4 u0 = *(const uint4*)&hp[(size_t)s0 * 512];
        f32x2 wv; wv.x = w0; wv.y = w0;
        acc[0] += unpack2(u0.x) * wv; acc[1] += unpack2(u0.y) * wv;
        acc[2] += unpack2(u0.z) * wv; acc[3] += unpack2(u0.w) * wv;
    }
    float rs = 1.f / (s + 1e-16f);
    int c = lane * 8;
    ushort_t o[8];
#pragma unroll
    for (int i = 0; i < 4; ++i) {
        float r0 = acc[i].x * rs + bias[c + 2 * i];
        float r1 = acc[i].y * rs + bias[c + 2 * i + 1];
        r0 = (r0 > 0.f) ? r0 : (__expf(r0) - 1.f);
        r1 = (r1 > 0.f) ? r1 : (__expf(r1) - 1.f);
        o[2 * i] = f2bf(r0);
        o[2 * i + 1] = f2bf(r1);
    }
    *(uint4*)&outb[(size_t)node * 512 + c] = *(uint4*)o;
}

// layer 2: wave per node, 1 head; same unnormalized-softmax structure; fp32 out.
__global__ __launch_bounds__(256) void gather2_kernel(
    const ushort_t* __restrict__ h2b, const float* __restrict__ e_src,
    const float* __restrict__ e_dst, const int* __restrict__ offsets,
    const int* __restrict__ csr_src, const float* __restrict__ bias,
    float* __restrict__ out, int N)
{
    int node = __builtin_amdgcn_readfirstlane(blockIdx.x * 4 + (threadIdx.x >> 6));
    int lane = threadIdx.x & 63;
    if (node >= N) return;
    int beg = offsets[node], end = offsets[node + 1];
    float ed = e_dst[node];

    const ushort_t* hp = h2b + lane * 2;
    f32x2 acc = { 0.f, 0.f };
    float s = 0.f;
    int j = beg;
#pragma unroll 2
    for (; j + 4 <= end; j += 4) {
        int s0 = csr_src[j], s1 = csr_src[j + 1];
        int s2 = csr_src[j + 2], s3 = csr_src[j + 3];
        float w0 = __expf(leaky(e_src[s0] + ed));
        float w1 = __expf(leaky(e_src[s1] + ed));
        float w2 = __expf(leaky(e_src[s2] + ed));
        float w3 = __expf(leaky(e_src[s3] + ed));
        s += (w0 + w1) + (w2 + w3);
        unsigned u0 = *(const unsigned*)&hp[(size_t)s0 * 128];
        unsigned u1 = *(const unsigned*)&hp[(size_t)s1 * 128];
        unsigned u2 = *(const unsigned*)&hp[(size_t)s2 * 128];
        unsigned u3 = *(const unsigned*)&hp[(size_t)s3 * 128];
        f32x2 w0v = { w0, w0 }, w1v = { w1, w1 }, w2v = { w2, w2 }, w3v = { w3, w3 };
        acc += unpack2(u0) * w0v;
        acc += unpack2(u1) * w1v;
        acc += unpack2(u2) * w2v;
        acc += unpack2(u3) * w3v;
    }
    for (; j < end; ++j) {
        int s0 = csr_src[j];
        float w0 = __expf(leaky(e_src[s0] + ed));
        s += w0;
        unsigned u0 = *(const unsigned*)&hp[(size_t)s0 * 128];
        f32x2 w0v = { w0, w0 };
        acc += unpack2(u0) * w0v;
    }
    float rs = 1.f / (s + 1e-16f);
    float2 o = make_float2(acc.x * rs + bias[lane * 2], acc.y * rs + bias[lane * 2 + 1]);
    *(float2*)&out[(size_t)node * 128 + lane * 2] = o;
}

// ---------------------------------------------------------------- launch
extern "C" void kernel_launch(void* const* d_in, const int* in_sizes, int n_in,
                              void* d_out, int out_size, void* d_ws, size_t ws_size,
                              hipStream_t stream) {
    const float* x      = (const float*)d_in[0];
    const int*   ei     = (const int*)  d_in[1];
    const float* sent   = (const float*)d_in[2];
    const float* W1     = (const float*)d_in[3];
    const float* a1_src = (const float*)d_in[4];
    const float* a1_dst = (const float*)d_in[5];
    const float* b1     = (const float*)d_in[6];
    const float* W2     = (const float*)d_in[7];
    const float* a2_src = (const float*)d_in[8];
    const float* a2_dst = (const float*)d_in[9];
    const float* b2     = (const float*)d_in[10];
    float* out = (float*)d_out;

    const int N = in_sizes[0] / 768;   // 20000
    const int E = in_sizes[1] / 2;     // 320000

    char* p = (char*)d_ws;
    auto carve = [&](size_t bytes) {
        char* q = p;
        p += (bytes + 255) & ~(size_t)255;
        return q;
    };
    ushort_t* h1b = (ushort_t*)carve((size_t)N * 512 * 2);
    ushort_t* h_elu_b = (ushort_t*)carve((size_t)N * 512 * 2);
    ushort_t* h2b = (ushort_t*)carve((size_t)N * 128 * 2);
    ushort_t* W1T = (ushort_t*)carve((size_t)512 * 768 * 2);
    ushort_t* W2T = (ushort_t*)carve((size_t)128 * 512 * 2);
    float* svec_part = (float*)carve(8 * 512 * 4);
    float* svec   = (float*)carve(512 * 4);
    float* e_src1 = (float*)carve((size_t)N * 4 * 4);
    float* e_dst1 = (float*)carve((size_t)N * 4 * 4);
    float* e_src2 = (float*)carve((size_t)N * 4);
    float* e_dst2 = (float*)carve((size_t)N * 4);
    int*   indeg  = (int*)carve((size_t)N * 4);
    int*   offs   = (int*)carve((size_t)(N + 1) * 4);
    int*   cursor = (int*)carve((size_t)N * 4);
    int*   csrsrc = (int*)carve((size_t)E * 4);

    int nbZero = (N + 255) / 256;
    int nbPrep = 384 + 64 + 16 + nbZero;

    // fused prep: transpose W1/W2, svec partials, zero indeg (x cast removed)
    prep_kernel<<<nbPrep, 256, 0, stream>>>(W1, W1T, W2, W2T,
                                            sent, svec_part, indeg, N, nbZero);
    // CSR build (+ svec reduce inside scan)
    count_kernel<<<(E + 255) / 256, 256, 0, stream>>>(ei, indeg, E);
    scan_kernel<<<1, 1024, 0, stream>>>(indeg, offs, cursor, svec_part, svec, N);
    scatter_kernel<<<(E + 255) / 256, 256, 0, stream>>>(ei, cursor, csrsrc, E);

    // pad row-block count to a multiple of 8 so the XCD swizzle is bijective;
    // padded blocks clamp their A rows and skip all guarded writes.
    int nyPad = (((N + 127) / 128) + 7) & ~7;   // 160 for N=20000

    // GEMM1: h1b = bf16(x @ W1[:768] + svec), fused e1, fused fp32->bf16 cast
    mfma_gemm_kernel<true><<<dim3(4, nyPad), 256, 0, stream>>>(
        x, W1T, svec, h1b, a1_src, a1_dst, e_src1, e_dst1, 4, N, 768, 512);

    // layer-1 attention (unnormalized softmax fused into gather)
    gather1_kernel<<<(N + 3) / 4, 256, 0, stream>>>(
        h1b, e_src1, e_dst1, offs, csrsrc, b1, h_elu_b, N);

    // GEMM2: h2b = bf16(h_elu @ W2), fused e2  [N,128]
    mfma_gemm_kernel<false><<<dim3(1, nyPad), 256, 0, stream>>>(
        h_elu_b, W2T, nullptr, h2b, a2_src, a2_dst, e_src2, e_dst2, 1, N, 512, 128);

    // layer-2 attention (fused)
    gather2_kernel<<<(N + 3) / 4, 256, 0, stream>>>(
        h2b, e_src2, e_dst2, offs, csrsrc, b2, out, N);
}

// Round 4
// 281.906 us; speedup vs baseline: 1.0795x; 1.0795x over previous
//
#include <hip/hip_runtime.h>
#include <cstdint>
#include <cstddef>

#define NSLOPE 0.2f

typedef __attribute__((ext_vector_type(8))) short bf16x8;
typedef __attribute__((ext_vector_type(4))) float f32x4;
typedef __attribute__((ext_vector_type(2))) float f32x2;
typedef unsigned short ushort_t;

// ---------------------------------------------------------------- utilities
__device__ inline ushort_t f2bf(float f) {
    union { float f; unsigned u; } v; v.f = f;
    unsigned u = v.u;
    unsigned r = (u + 0x7fffu + ((u >> 16) & 1u)) >> 16;   // RNE
    return (ushort_t)r;
}
// optimal 2-op unpack: lo = u<<16, hi = u & 0xffff0000
__device__ inline f32x2 unpack2(unsigned u) {
    union { unsigned u; float f; } lo, hi;
    lo.u = u << 16;
    hi.u = u & 0xffff0000u;
    f32x2 r; r.x = lo.f; r.y = hi.f;
    return r;
}
__device__ inline float leaky(float v) { return (v > 0.f) ? v : NSLOPE * v; }
__device__ inline float sel4(float4 q, bool b1, bool b2) {
    return b2 ? (b1 ? q.w : q.z) : (b1 ? q.y : q.x);
}

// ---------------------------------------------------------------- fused prep
// sections: [0,nbCast) cast x->bf16 | [.. +384) transpose W1 | [.. +64)
// transpose W2 | [.. +16) svec partials | [.. +nbZero) zero indeg
// (R3's fused-cast-into-GEMM regressed: vmcnt(8) mid-loop stall cost +32us vs
// the ~15us this pass costs. Restored.)
__global__ __launch_bounds__(256) void prep_kernel(
    const float* __restrict__ x, ushort_t* __restrict__ x_bf16, size_t nx,
    const float* __restrict__ W1, ushort_t* __restrict__ W1T,
    const float* __restrict__ W2, ushort_t* __restrict__ W2T,
    const float* __restrict__ sent, float* __restrict__ svec_part,
    int* __restrict__ indeg, int N, int nbCast, int nbZero)
{
    __shared__ float tile[32][33];
    int bid = blockIdx.x;
    int tid = threadIdx.x;
    if (bid < nbCast) {
        size_t i = ((size_t)bid * 256 + tid) * 8;
        if (i < nx) {
            float4 v0 = *(const float4*)(x + i);
            float4 v1 = *(const float4*)(x + i + 4);
            ushort_t r[8] = { f2bf(v0.x), f2bf(v0.y), f2bf(v0.z), f2bf(v0.w),
                              f2bf(v1.x), f2bf(v1.y), f2bf(v1.z), f2bf(v1.w) };
            *(uint4*)(x_bf16 + i) = *(uint4*)r;
        }
        return;
    }
    bid -= nbCast;
    if (bid < 384) {   // W1[768][512] -> W1T[512][768]
        int k0 = (bid % 24) * 32, n0 = (bid / 24) * 32;
        int tx = tid & 31, ty = tid >> 5;
#pragma unroll
        for (int i = 0; i < 4; ++i)
            tile[ty + i * 8][tx] = W1[(size_t)(k0 + ty + i * 8) * 512 + n0 + tx];
        __syncthreads();
#pragma unroll
        for (int i = 0; i < 4; ++i)
            W1T[(size_t)(n0 + ty + i * 8) * 768 + k0 + tx] = f2bf(tile[tx][ty + i * 8]);
        return;
    }
    bid -= 384;
    if (bid < 64) {    // W2[512][128] -> W2T[128][512]
        int k0 = (bid % 16) * 32, n0 = (bid / 16) * 32;
        int tx = tid & 31, ty = tid >> 5;
#pragma unroll
        for (int i = 0; i < 4; ++i)
            tile[ty + i * 8][tx] = W2[(size_t)(k0 + ty + i * 8) * 128 + n0 + tx];
        __syncthreads();
#pragma unroll
        for (int i = 0; i < 4; ++i)
            W2T[(size_t)(n0 + ty + i * 8) * 512 + k0 + tx] = f2bf(tile[tx][ty + i * 8]);
        return;
    }
    bid -= 64;
    if (bid < 16) {    // svec partials
        int cb = bid & 1, kb = bid >> 1;
        int c = cb * 256 + tid;
        int k0 = kb * 96;
        float acc = 0.f;
#pragma unroll 8
        for (int k = k0; k < k0 + 96; ++k)
            acc += sent[k] * W1[(size_t)(768 + k) * 512 + c];
        svec_part[kb * 512 + c] = acc;
        return;
    }
    bid -= 16;
    {                  // zero indeg
        int i = bid * 256 + tid;
        if (i < N) indeg[i] = 0;
    }
}

// ---------------------------------------------------------------- MFMA GEMM
// 64-row x 128-col tiles (was 128x128): GEMM1 grid 640->1280 blocks, GEMM2
// 160->320. Rationale: 3 rounds showed GEMM1 duration invariant to FETCH,
// pipeline depth, and swizzle — all pipes ~11% busy, occupancy ~4 waves/CU.
// Binding constraint is blocks/CU (2.5) x barrier lockstep. 64-row tiles give
// 5 blocks/CU (LDS 37KB -> 4 resident) so stalls of one block overlap compute
// of another. Same 3-deep global_load_lds pipeline, counted vmcnt(3) (stage =
// 3 VMEM ops/thread: 1 A + 2 B). XCD-aware bijective swizzle keeps the 4
// col-blocks of each row-panel on one XCD (FETCH 61.6->20.0 MB measured).
// Fused attention-coefficient epilogue writes e_src/e_dst[row*eStride + bx].
__device__ inline void async_copy16(const void* g, void* l) {
    __builtin_amdgcn_global_load_lds(
        (const __attribute__((address_space(1))) unsigned int*)g,
        (__attribute__((address_space(3))) unsigned int*)l, 16, 0, 0);
}

__global__ __launch_bounds__(256) void mfma_gemm_kernel(
    const ushort_t* __restrict__ A,   // [M][K] bf16
    const ushort_t* __restrict__ BT,  // [Nc][K] bf16
    const float* __restrict__ bias,   // [Nc] or null
    ushort_t* __restrict__ Cb,        // [M][Nc] bf16
    const float* __restrict__ asrc,   // [Nc] flat attention vec (src)
    const float* __restrict__ adst,   // [Nc] flat attention vec (dst)
    float* __restrict__ e_src,        // [M*eStride]
    float* __restrict__ e_dst,
    int eStride,
    int M, int K, int Nc)
{
    __shared__ __align__(16) ushort_t lA[3][64 * 32];
    __shared__ __align__(16) ushort_t lB[3][128 * 32];
    __shared__ float e_lds[64][2][2];   // [row_local][col_half][src/dst]
    const int tid = threadIdx.x;
    const int wave = tid >> 6;
    const int lane = tid & 63;

    // bijective XCD swizzle (m204 form). Requires (gridDim.x*gridDim.y)%8==0.
    // Maps so all gridDim.x col-blocks of a row panel land on one XCD.
    const int hh = blockIdx.y * gridDim.x + blockIdx.x;
    const int xcd = hh & 7;
    const int slot = hh >> 3;
    const int by = xcd + 8 * (slot / gridDim.x);
    const int bx = slot % gridDim.x;

    const int col0 = bx * 128;
    const int row0 = by * 64;
    const int wm = (wave & 1) * 32;      // 2 waves over 64 rows
    const int wn = (wave >> 1) * 64;     // 2 waves over 128 cols
    const int q = lane >> 4;
    const int ml = lane & 15;

    f32x4 acc[2][4] = {};

    // A: 1 load/thread (64 rows x 4 chunks); B: 2 loads/thread (128 rows)
    const int rA = tid >> 2;
    const int gA = (tid & 3) ^ ((rA >> 1) & 3);
    int rowS[2], gS[2];
#pragma unroll
    for (int i = 0; i < 2; ++i) {
        int p = wave * 128 + i * 64 + lane;
        int r = p >> 2, s = p & 3;
        rowS[i] = r;
        gS[i] = s ^ ((r >> 1) & 3);
    }

    // 3 global_load_lds per thread per stage (1 A + 2 B); LDS dest must be
    // wave-uniform base (+lane*16 implicit in HW).
    auto stage = [&](int k0, int buf) {
        {
            int ga = min(row0 + rA, M - 1);
            async_copy16(A + (size_t)ga * K + k0 + gA * 8,
                         &lA[buf][(size_t)(wave * 64) * 8]);
        }
#pragma unroll
        for (int i = 0; i < 2; ++i) {
            int pbs = wave * 128 + i * 64;
            async_copy16(BT + (size_t)(col0 + rowS[i]) * K + k0 + gS[i] * 8,
                         &lB[buf][(size_t)pbs * 8]);
        }
    };

    const int nt = K >> 5;           // 24 (GEMM1) / 16 (GEMM2)
    stage(0, 0);
    if (nt > 1) {
        stage(32, 1);
        // in flight: tile0(3) tile1(3); wait tile0, keep tile1 flying
        asm volatile("s_waitcnt vmcnt(3)\n\ts_barrier" ::: "memory");
    } else {
        asm volatile("s_waitcnt vmcnt(0)\n\ts_barrier" ::: "memory");
    }

    for (int t = 0; t < nt; ++t) {
        const int pb = t % 3;
        // stage writes buf[(t+2)%3] == buf[(t-1)%3]: its readers (iter t-1)
        // all passed the barrier that ended iter t-1 (with lgkmcnt drained).
        if (t + 2 < nt) stage((t + 2) << 5, (t + 2) % 3);
        bf16x8 af[2], bfr[4];
#pragma unroll
        for (int tt = 0; tt < 2; ++tt) {
            int m = wm + tt * 16 + ml;
            af[tt] = *(const bf16x8*)&lA[pb][(size_t)(m * 4 + (q ^ ((m >> 1) & 3))) * 8];
        }
#pragma unroll
        for (int tt = 0; tt < 4; ++tt) {
            int n = wn + tt * 16 + ml;
            bfr[tt] = *(const bf16x8*)&lB[pb][(size_t)(n * 4 + (q ^ ((n >> 1) & 3))) * 8];
        }
#pragma unroll
        for (int tm = 0; tm < 2; ++tm)
#pragma unroll
            for (int tn = 0; tn < 4; ++tn)
                acc[tm][tn] = __builtin_amdgcn_mfma_f32_16x16x32_bf16(
                    af[tm], bfr[tn], acc[tm][tn], 0, 0, 0);
        // end-of-iter: tile t+1 landed (mine via vmcnt, everyone's via
        // barrier); lgkmcnt(0) so no ds_read is still queued when the next
        // iter's stage overwrites this buffer. Tile t+2 stays IN FLIGHT.
        if (t + 2 < nt)
            asm volatile("s_waitcnt vmcnt(3) lgkmcnt(0)\n\ts_barrier" ::: "memory");
        else if (t + 1 < nt)
            asm volatile("s_waitcnt vmcnt(0) lgkmcnt(0)\n\ts_barrier" ::: "memory");
        // last iteration: no barrier needed; epilogue __syncthreads covers e_lds.
    }

    float es_acc[2][4] = {};   // [tm][r]
    float ed_acc[2][4] = {};
#pragma unroll
    for (int tm = 0; tm < 2; ++tm) {
        int rbase = row0 + wm + tm * 16 + q * 4;
#pragma unroll
        for (int tn = 0; tn < 4; ++tn) {
            int col = col0 + wn + tn * 16 + ml;
            float bb = bias ? bias[col] : 0.f;
            float av = asrc[col];
            float dv = adst[col];
#pragma unroll
            for (int r = 0; r < 4; ++r) {
                int row = rbase + r;
                float val = acc[tm][tn][r] + bb;
                if (row < M)
                    Cb[(size_t)row * Nc + col] = f2bf(val);
                es_acc[tm][r] += val * av;
                ed_acc[tm][r] += val * dv;
            }
        }
    }
    // reduce over the 16-lane col groups (xor 1,2,4,8 keeps q fixed)
    const int colhalf = wave >> 1;
#pragma unroll
    for (int tm = 0; tm < 2; ++tm) {
#pragma unroll
        for (int r = 0; r < 4; ++r) {
            float es = es_acc[tm][r], ed2 = ed_acc[tm][r];
#pragma unroll
            for (int st = 1; st < 16; st <<= 1) {
                es += __shfl_xor(es, st);
                ed2 += __shfl_xor(ed2, st);
            }
            if (ml == 0) {
                int rl = wm + tm * 16 + q * 4 + r;
                e_lds[rl][colhalf][0] = es;
                e_lds[rl][colhalf][1] = ed2;
            }
        }
    }
    __syncthreads();
    if (tid < 64) {
        int row = row0 + tid;
        if (row < M) {
            float es = e_lds[tid][0][0] + e_lds[tid][1][0];
            float ed2 = e_lds[tid][0][1] + e_lds[tid][1][1];
            e_src[(size_t)row * eStride + bx] = es;
            e_dst[(size_t)row * eStride + bx] = ed2;
        }
    }
}

// ---------------------------------------------------------------- CSR build
__global__ void count_kernel(const int* __restrict__ ei, int* __restrict__ indeg, int E) {
    int e = blockIdx.x * blockDim.x + threadIdx.x;
    if (e < E) atomicAdd(&indeg[ei[E + e]], 1);
}

__global__ __launch_bounds__(1024) void scan_kernel(const int* __restrict__ indeg,
                                                    int* __restrict__ offsets,
                                                    int* __restrict__ cursor,
                                                    const float* __restrict__ svec_part,
                                                    float* __restrict__ svec, int N) {
    __shared__ int partial[1024];
    int tid = threadIdx.x;
    if (tid < 512) {
        float s = 0.f;
#pragma unroll
        for (int kb = 0; kb < 8; ++kb) s += svec_part[kb * 512 + tid];
        svec[tid] = s;
    }
    int per = (N + 1023) / 1024;
    int start = tid * per;
    int end = min(start + per, N);
    int sum = 0;
    if (start + per <= N && (per & 3) == 0) {
        for (int i = 0; i < per; i += 4) {
            int4 v = *(const int4*)(indeg + start + i);
            sum += v.x + v.y + v.z + v.w;
        }
    } else {
        for (int i = start; i < end; ++i) sum += indeg[i];
    }
    partial[tid] = sum;
    __syncthreads();
    for (int st = 1; st < 1024; st <<= 1) {
        int v = (tid >= st) ? partial[tid - st] : 0;
        __syncthreads();
        partial[tid] += v;
        __syncthreads();
    }
    int run = (tid == 0) ? 0 : partial[tid - 1];
    if (start + per <= N && (per & 3) == 0) {
        for (int i = 0; i < per; i += 4) {
            int4 v = *(const int4*)(indeg + start + i);
            int4 o;
            o.x = run;
            o.y = o.x + v.x;
            o.z = o.y + v.y;
            o.w = o.z + v.z;
            run = o.w + v.w;
            *(int4*)(offsets + start + i) = o;
            *(int4*)(cursor + start + i) = o;
        }
    } else {
        for (int i = start; i < end; ++i) {
            offsets[i] = run; cursor[i] = run;
            run += indeg[i];
        }
    }
    if (tid == 1023) offsets[N] = run;
}

__global__ void scatter_kernel(const int* __restrict__ ei, int* __restrict__ cursor,
                               int* __restrict__ csr_src, int E) {
    int e = blockIdx.x * blockDim.x + threadIdx.x;
    if (e < E) {
        int d = ei[E + e];
        int p = atomicAdd(&cursor[d], 1);
        csr_src[p] = ei[e];
    }
}

// ---------------------------------------------------------------- gather+softmax
// layer 1: wave per node. Unnormalized softmax: degrees are small (Poisson(16))
// and e = leaky(e_src+e_dst) is bounded (max ~11 << 88 = fp32 exp overflow), so
// accumulate w = exp(e) and redundant per-lane s = sum(w); scale by 1/s at end.
__global__ __launch_bounds__(256) void gather1_kernel(
    const ushort_t* __restrict__ h1b, const float* __restrict__ e_src,
    const float* __restrict__ e_dst, const int* __restrict__ offsets,
    const int* __restrict__ csr_src, const float* __restrict__ bias,
    ushort_t* __restrict__ outb, int N)
{
    int node = __builtin_amdgcn_readfirstlane(blockIdx.x * 4 + (threadIdx.x >> 6));
    int lane = threadIdx.x & 63;
    if (node >= N) return;
    int beg = offsets[node], end = offsets[node + 1];
    float4 ed = *(const float4*)&e_dst[node * 4];

    // per-lane head constants
    const int h = lane >> 4;
    const bool b1 = (h & 1), b2 = (h & 2);
    float edh = sel4(ed, b1, b2);

    const ushort_t* hp = h1b + lane * 8;
    f32x2 acc[4] = {};
    float s = 0.f;                       // same value in every lane of a head
    int j = beg;
#pragma unroll 2
    for (; j + 4 <= end; j += 4) {
        int s0 = csr_src[j], s1 = csr_src[j + 1];          // scalar
        int s2 = csr_src[j + 2], s3 = csr_src[j + 3];
        float4 q0 = *(const float4*)&e_src[s0 * 4];        // scalar 16B
        float4 q1 = *(const float4*)&e_src[s1 * 4];
        float4 q2 = *(const float4*)&e_src[s2 * 4];
        float4 q3 = *(const float4*)&e_src[s3 * 4];
        float w0 = __expf(leaky(sel4(q0, b1, b2) + edh));
        float w1 = __expf(leaky(sel4(q1, b1, b2) + edh));
        float w2 = __expf(leaky(sel4(q2, b1, b2) + edh));
        float w3 = __expf(leaky(sel4(q3, b1, b2) + edh));
        s += (w0 + w1) + (w2 + w3);
        uint4 u0 = *(const uint4*)&hp[(size_t)s0 * 512];
        uint4 u1 = *(const uint4*)&hp[(size_t)s1 * 512];
        uint4 u2 = *(const uint4*)&hp[(size_t)s2 * 512];
        uint4 u3 = *(const uint4*)&hp[(size_t)s3 * 512];
        f32x2 wv;
        wv.x = w0; wv.y = w0;
        acc[0] += unpack2(u0.x) * wv; acc[1] += unpack2(u0.y) * wv;
        acc[2] += unpack2(u0.z) * wv; acc[3] += unpack2(u0.w) * wv;
        wv.x = w1; wv.y = w1;
        acc[0] += unpack2(u1.x) * wv; acc[1] += unpack2(u1.y) * wv;
        acc[2] += unpack2(u1.z) * wv; acc[3] += unpack2(u1.w) * wv;
        wv.x = w2; wv.y = w2;
        acc[0] += unpack2(u2.x) * wv; acc[1] += unpack2(u2.y) * wv;
        acc[2] += unpack2(u2.z) * wv; acc[3] += unpack2(u2.w) * wv;
        wv.x = w3; wv.y = w3;
        acc[0] += unpack2(u3.x) * wv; acc[1] += unpack2(u3.y) * wv;
        acc[2] += unpack2(u3.z) * wv; acc[3] += unpack2(u3.w) * wv;
    }
    for (; j < end; ++j) {
        int s0 = csr_src[j];
        float4 q0 = *(const float4*)&e_src[s0 * 4];
        float w0 = __expf(leaky(sel4(q0, b1, b2) + edh));
        s += w0;
        uint4 u0 = *(const uint4*)&hp[(size_t)s0 * 512];
        f32x2 wv; wv.x = w0; wv.y = w0;
        acc[0] += unpack2(u0.x) * wv; acc[1] += unpack2(u0.y) * wv;
        acc[2] += unpack2(u0.z) * wv; acc[3] += unpack2(u0.w) * wv;
    }
    float rs = 1.f / (s + 1e-16f);
    int c = lane * 8;
    ushort_t o[8];
#pragma unroll
    for (int i = 0; i < 4; ++i) {
        float r0 = acc[i].x * rs + bias[c + 2 * i];
        float r1 = acc[i].y * rs + bias[c + 2 * i + 1];
        r0 = (r0 > 0.f) ? r0 : (__expf(r0) - 1.f);
        r1 = (r1 > 0.f) ? r1 : (__expf(r1) - 1.f);
        o[2 * i] = f2bf(r0);
        o[2 * i + 1] = f2bf(r1);
    }
    *(uint4*)&outb[(size_t)node * 512 + c] = *(uint4*)o;
}

// layer 2: wave per node, 1 head; same unnormalized-softmax structure; fp32 out.
__global__ __launch_bounds__(256) void gather2_kernel(
    const ushort_t* __restrict__ h2b, const float* __restrict__ e_src,
    const float* __restrict__ e_dst, const int* __restrict__ offsets,
    const int* __restrict__ csr_src, const float* __restrict__ bias,
    float* __restrict__ out, int N)
{
    int node = __builtin_amdgcn_readfirstlane(blockIdx.x * 4 + (threadIdx.x >> 6));
    int lane = threadIdx.x & 63;
    if (node >= N) return;
    int beg = offsets[node], end = offsets[node + 1];
    float ed = e_dst[node];

    const ushort_t* hp = h2b + lane * 2;
    f32x2 acc = { 0.f, 0.f };
    float s = 0.f;
    int j = beg;
#pragma unroll 2
    for (; j + 4 <= end; j += 4) {
        int s0 = csr_src[j], s1 = csr_src[j + 1];
        int s2 = csr_src[j + 2], s3 = csr_src[j + 3];
        float w0 = __expf(leaky(e_src[s0] + ed));
        float w1 = __expf(leaky(e_src[s1] + ed));
        float w2 = __expf(leaky(e_src[s2] + ed));
        float w3 = __expf(leaky(e_src[s3] + ed));
        s += (w0 + w1) + (w2 + w3);
        unsigned u0 = *(const unsigned*)&hp[(size_t)s0 * 128];
        unsigned u1 = *(const unsigned*)&hp[(size_t)s1 * 128];
        unsigned u2 = *(const unsigned*)&hp[(size_t)s2 * 128];
        unsigned u3 = *(const unsigned*)&hp[(size_t)s3 * 128];
        f32x2 w0v = { w0, w0 }, w1v = { w1, w1 }, w2v = { w2, w2 }, w3v = { w3, w3 };
        acc += unpack2(u0) * w0v;
        acc += unpack2(u1) * w1v;
        acc += unpack2(u2) * w2v;
        acc += unpack2(u3) * w3v;
    }
    for (; j < end; ++j) {
        int s0 = csr_src[j];
        float w0 = __expf(leaky(e_src[s0] + ed));
        s += w0;
        unsigned u0 = *(const unsigned*)&hp[(size_t)s0 * 128];
        f32x2 w0v = { w0, w0 };
        acc += unpack2(u0) * w0v;
    }
    float rs = 1.f / (s + 1e-16f);
    float2 o = make_float2(acc.x * rs + bias[lane * 2], acc.y * rs + bias[lane * 2 + 1]);
    *(float2*)&out[(size_t)node * 128 + lane * 2] = o;
}

// ---------------------------------------------------------------- launch
extern "C" void kernel_launch(void* const* d_in, const int* in_sizes, int n_in,
                              void* d_out, int out_size, void* d_ws, size_t ws_size,
                              hipStream_t stream) {
    const float* x      = (const float*)d_in[0];
    const int*   ei     = (const int*)  d_in[1];
    const float* sent   = (const float*)d_in[2];
    const float* W1     = (const float*)d_in[3];
    const float* a1_src = (const float*)d_in[4];
    const float* a1_dst = (const float*)d_in[5];
    const float* b1     = (const float*)d_in[6];
    const float* W2     = (const float*)d_in[7];
    const float* a2_src = (const float*)d_in[8];
    const float* a2_dst = (const float*)d_in[9];
    const float* b2     = (const float*)d_in[10];
    float* out = (float*)d_out;

    const int N = in_sizes[0] / 768;   // 20000
    const int E = in_sizes[1] / 2;     // 320000

    char* p = (char*)d_ws;
    auto carve = [&](size_t bytes) {
        char* q = p;
        p += (bytes + 255) & ~(size_t)255;
        return q;
    };
    ushort_t* h1b = (ushort_t*)carve((size_t)N * 512 * 2);
    char* shared_region = carve((size_t)N * 768 * 2);   // x_bf16 dead after GEMM1
    ushort_t* x_bf16 = (ushort_t*)shared_region;
    ushort_t* h_elu_b = (ushort_t*)shared_region;
    ushort_t* h2b = (ushort_t*)carve((size_t)N * 128 * 2);
    ushort_t* W1T = (ushort_t*)carve((size_t)512 * 768 * 2);
    ushort_t* W2T = (ushort_t*)carve((size_t)128 * 512 * 2);
    float* svec_part = (float*)carve(8 * 512 * 4);
    float* svec   = (float*)carve(512 * 4);
    float* e_src1 = (float*)carve((size_t)N * 4 * 4);
    float* e_dst1 = (float*)carve((size_t)N * 4 * 4);
    float* e_src2 = (float*)carve((size_t)N * 4);
    float* e_dst2 = (float*)carve((size_t)N * 4);
    int*   indeg  = (int*)carve((size_t)N * 4);
    int*   offs   = (int*)carve((size_t)(N + 1) * 4);
    int*   cursor = (int*)carve((size_t)N * 4);
    int*   csrsrc = (int*)carve((size_t)E * 4);

    size_t nx = (size_t)N * 768;
    int nbCast = (int)((nx / 8 + 255) / 256);
    int nbZero = (N + 255) / 256;
    int nbPrep = nbCast + 384 + 64 + 16 + nbZero;

    // fused prep: cast x, transpose W1/W2, svec partials, zero indeg
    prep_kernel<<<nbPrep, 256, 0, stream>>>(x, x_bf16, nx, W1, W1T, W2, W2T,
                                            sent, svec_part, indeg, N, nbCast, nbZero);
    // CSR build (+ svec reduce inside scan)
    count_kernel<<<(E + 255) / 256, 256, 0, stream>>>(ei, indeg, E);
    scan_kernel<<<1, 1024, 0, stream>>>(indeg, offs, cursor, svec_part, svec, N);
    scatter_kernel<<<(E + 255) / 256, 256, 0, stream>>>(ei, cursor, csrsrc, E);

    // pad row-block count (64-row tiles) to a multiple of 8 for the XCD
    // swizzle; padded blocks clamp their A rows and skip all guarded writes.
    int nyPad = (((N + 63) / 64) + 7) & ~7;   // 320 for N=20000

    // GEMM1: h1b = bf16(x @ W1[:768] + svec), fused e1  [N,512]
    mfma_gemm_kernel<<<dim3(4, nyPad), 256, 0, stream>>>(
        x_bf16, W1T, svec, h1b, a1_src, a1_dst, e_src1, e_dst1, 4, N, 768, 512);

    // layer-1 attention (unnormalized softmax fused into gather)
    gather1_kernel<<<(N + 3) / 4, 256, 0, stream>>>(
        h1b, e_src1, e_dst1, offs, csrsrc, b1, h_elu_b, N);

    // GEMM2: h2b = bf16(h_elu @ W2), fused e2  [N,128]
    mfma_gemm_kernel<<<dim3(1, nyPad), 256, 0, stream>>>(
        h_elu_b, W2T, nullptr, h2b, a2_src, a2_dst, e_src2, e_dst2, 1, N, 512, 128);

    // layer-2 attention (fused)
    gather2_kernel<<<(N + 3) / 4, 256, 0, stream>>>(
        h2b, e_src2, e_dst2, offs, csrsrc, b2, out, N);
}